// Round 5
// baseline (866.404 us; speedup 1.0000x reference)
//
#include <hip/hip_runtime.h>
#include <hip/hip_bf16.h>
#include <stdint.h>

// ---------------------------------------------------------------------------
// TemporalAttention fused pipeline:
//   q = (query@Wq+bq)*scale ; k = keys@Wk+bk ; v = k@Wv+bv (vT materialized)
//   context = softmax(q k^T) v   via flash-attention fused kernel.
// B=16, LQ=1024, LK=4096, D=512. bf16 MFMA, fp32 accum.
// ---------------------------------------------------------------------------

typedef __attribute__((ext_vector_type(8))) short bf16x8;
typedef __attribute__((ext_vector_type(4))) float f32x4;
typedef __attribute__((ext_vector_type(16))) float f32x16;
typedef __attribute__((ext_vector_type(8))) unsigned short ushort8v;
typedef __attribute__((ext_vector_type(4))) unsigned short ushort4v;

__device__ __forceinline__ unsigned short f2bf(float f) {
  union { float f; unsigned int u; } x{f};
  unsigned int r = x.u + 0x7FFFu + ((x.u >> 16) & 1u);
  return (unsigned short)(r >> 16);
}
__device__ __forceinline__ float bf2f(unsigned short h) {
  union { unsigned int u; float f; } x{(unsigned int)h << 16};
  return x.f;
}

#define GLOAD_LDS16(gptr, lptr)                                                  \
  __builtin_amdgcn_global_load_lds((const __attribute__((address_space(1))) void*)(gptr), \
                                   (__attribute__((address_space(3))) void*)(lptr), 16, 0, 0)

// ---------------------------------------------------------------------------
// Cast fp32 -> bf16 (vectorized, grid-stride)
// ---------------------------------------------------------------------------
__global__ __launch_bounds__(256) void cast_bf16_kernel(const float* __restrict__ in,
                                                        unsigned short* __restrict__ out,
                                                        long n) {
  long i = ((long)blockIdx.x * blockDim.x + threadIdx.x) * 8;
  long stride = (long)gridDim.x * blockDim.x * 8;
  for (; i < n; i += stride) {
    const float4* p = (const float4*)(in + i);
    float4 a = p[0], b = p[1];
    ushort8v o;
    o[0] = f2bf(a.x); o[1] = f2bf(a.y); o[2] = f2bf(a.z); o[3] = f2bf(a.w);
    o[4] = f2bf(b.x); o[5] = f2bf(b.y); o[6] = f2bf(b.z); o[7] = f2bf(b.w);
    *(ushort8v*)(out + i) = o;
  }
}

// ---------------------------------------------------------------------------
// Transpose 512x512 fp32 W -> bf16 W^T (3 matrices via blockIdx.z)
// ---------------------------------------------------------------------------
__global__ __launch_bounds__(256) void transpose_w_kernel(const float* __restrict__ W0,
                                                          const float* __restrict__ W1,
                                                          const float* __restrict__ W2,
                                                          unsigned short* __restrict__ T0,
                                                          unsigned short* __restrict__ T1,
                                                          unsigned short* __restrict__ T2) {
  const float* W = (blockIdx.z == 0) ? W0 : (blockIdx.z == 1) ? W1 : W2;
  unsigned short* T = (blockIdx.z == 0) ? T0 : (blockIdx.z == 1) ? T1 : T2;
  __shared__ float tile[32][33];
  int tx = threadIdx.x & 31, ty = threadIdx.x >> 5;  // 32 x 8
  int gx = blockIdx.x * 32 + tx;
  int gy0 = blockIdx.y * 32;
#pragma unroll
  for (int i = 0; i < 32; i += 8) tile[ty + i][tx] = W[(size_t)(gy0 + ty + i) * 512 + gx];
  __syncthreads();
  int ox = blockIdx.y * 32 + tx;
  int oy0 = blockIdx.x * 32;
#pragma unroll
  for (int i = 0; i < 32; i += 8)
    T[(size_t)(oy0 + ty + i) * 512 + ox] = f2bf(tile[tx][ty + i]);
}

// ---------------------------------------------------------------------------
// NT GEMM (projections): C[m][n] = (sum_k A[m][k]*Bt[n][k] + bias[n]) * scale
// OUT_MODE: 0 = bf16 C[m][n]; 1 = bf16 vT special (b=m>>12, C[(b*512+n)*4096+(m&4095)])
// Tile 128x128, BK=64, 256 threads (4 waves, 2x2), 16x16x32 bf16 MFMA.
// ---------------------------------------------------------------------------
template <int OUT_MODE>
__global__ __launch_bounds__(256, 2) void gemm_nt(const unsigned short* __restrict__ A,
                                                  const unsigned short* __restrict__ Bt,
                                                  const float* __restrict__ bias,
                                                  void* __restrict__ Cout,
                                                  int M, int N, int K, float scale) {
  __shared__ __align__(16) unsigned short lA[2][128][64];
  __shared__ __align__(16) unsigned short lB[2][128][64];
  const int tid = threadIdx.x;
  const int lane = tid & 63;
  const int wave = tid >> 6;
  const int m0 = blockIdx.y * 128;
  const int n0 = blockIdx.x * 128;

  f32x4 acc[4][4] = {};

  auto stage = [&](int buf, int kt) {
    const int k0 = kt * 64;
#pragma unroll
    for (int p = 0; p < 4; ++p) {
      int c = p * 4 + wave;          // chunk 0..15, 1KB each
      int f = c * 512 + lane * 8;    // flat ushort index
      int row = f >> 6, col = f & 63;
      const unsigned short* gA = A + (size_t)(m0 + row) * K + (k0 + col);
      const unsigned short* gB = Bt + (size_t)(n0 + row) * K + (k0 + col);
      GLOAD_LDS16(gA, &lA[buf][0][0] + c * 512);
      GLOAD_LDS16(gB, &lB[buf][0][0] + c * 512);
    }
  };

  const int wm = wave >> 1, wn = wave & 1;
  const int lr = lane & 15;
  const int lk = (lane >> 4) << 3;

  const int KT = K >> 6;
  stage(0, 0);
  __syncthreads();
  int cur = 0;
  for (int kt = 0; kt < KT; ++kt) {
    if (kt + 1 < KT) stage(cur ^ 1, kt + 1);
#pragma unroll
    for (int kk = 0; kk < 64; kk += 32) {
      bf16x8 af[4], bfv[4];
#pragma unroll
      for (int i = 0; i < 4; ++i)
        af[i] = *(const bf16x8*)&lA[cur][wm * 64 + i * 16 + lr][kk + lk];
#pragma unroll
      for (int j = 0; j < 4; ++j)
        bfv[j] = *(const bf16x8*)&lB[cur][wn * 64 + j * 16 + lr][kk + lk];
#pragma unroll
      for (int i = 0; i < 4; ++i)
#pragma unroll
        for (int j = 0; j < 4; ++j)
          acc[i][j] = __builtin_amdgcn_mfma_f32_16x16x32_bf16(af[i], bfv[j], acc[i][j], 0, 0, 0);
    }
    __syncthreads();
    cur ^= 1;
  }

  const int ci = lane & 15;
  const int ri = (lane >> 4) * 4;
#pragma unroll
  for (int i = 0; i < 4; ++i) {
#pragma unroll
    for (int j = 0; j < 4; ++j) {
      int gm = m0 + wm * 64 + i * 16 + ri;
      int gn = n0 + wn * 64 + j * 16 + ci;
      float bv_ = bias[gn];
      f32x4 a = acc[i][j];
      if (OUT_MODE == 0) {
        unsigned short* C = (unsigned short*)Cout;
#pragma unroll
        for (int r = 0; r < 4; ++r)
          C[(size_t)(gm + r) * N + gn] = f2bf((a[r] + bv_) * scale);
      } else {  // vT: rows m are kv rows over all batches, cols n are dims
        unsigned short* C = (unsigned short*)Cout;
        int b_ = gm >> 12;
        int ml = gm & 4095;
        ushort4v pk;
#pragma unroll
        for (int r = 0; r < 4; ++r) pk[r] = f2bf((a[r] + bv_) * scale);
        *(ushort4v*)&C[((size_t)b_ * 512 + gn) * 4096 + ml] = pk;
      }
    }
  }
}

// ---------------------------------------------------------------------------
// Flash attention v3: out[b][q][d] = softmax_kv(qk^T) @ v
//   q: [16][1024][512] bf16 (scale pre-folded), k: [16][4096][512] bf16,
//   vT: [16][512][4096] bf16, out fp32.
// Block: 512 thr (8 waves), QBLK=32, KVBLK=256, 16 KV tiles, 32x32x16 MFMA.
// Wave w owns kv rows [w*32,w*32+32) for QK^T (K direct from global, no dup)
// and d-slice [w*64,w*64+64) for PV (V direct from global).
// Q in swizzled LDS (32KB); lP double-buffered (2x16KB); 3 barriers/tile.
// Target: VGPR<=128 -> 2 blocks/CU (4 waves/SIMD).
// ---------------------------------------------------------------------------
__global__ __launch_bounds__(512, 4) void flash_attn(const unsigned short* __restrict__ q,
                                                     const unsigned short* __restrict__ k,
                                                     const unsigned short* __restrict__ vT,
                                                     float* __restrict__ out) {
  __shared__ __align__(16) unsigned short lQ[32 * 512];      // 32 KB, swizzled
  __shared__ __align__(16) unsigned short lP[2][32 * 256];   // 2 x 16 KB, swizzled
  __shared__ __align__(16) float redm[32 * 8], reds[32 * 8]; // 2 KB
  __shared__ float m_s[32], rs_s[32];                        // 256 B

  const int tid = threadIdx.x;
  const int lane = tid & 63;
  const int w = tid >> 6;
  const int h = lane >> 5;        // half-wave 0/1
  const int c31 = lane & 31;
  const int bid = blockIdx.x;
  // bijective XCD swizzle: XCD c (= bid%8) serves batches {2c, 2c+1}
  const int idx = bid >> 3;            // 0..63
  const int b = (bid & 7) * 2 + (idx >> 5);
  const int qt = idx & 31;             // 32 q-tiles of 32 rows

  const unsigned short* Qb = q + ((size_t)b * 1024 + qt * 32) * 512;
  const unsigned short* Kb = k + (size_t)b * 4096 * 512;
  const unsigned short* Vb = vT + (size_t)b * 512 * 4096;

  // prologue: stage Q via gload_lds (pre-swizzled source, linear dest). 32KB.
#pragma unroll
  for (int i = 0; i < 4; ++i) {
    int byte = (i * 512 + tid) * 16;
    int row = byte >> 10;
    int colB = byte & 1023;
    int srcB = (colB & ~127) | ((colB & 127) ^ ((row & 7) << 4));
    GLOAD_LDS16(Qb + (size_t)row * 512 + (srcB >> 1), (char*)lQ + byte);
  }
  float m_run = -1e30f, l_run = 0.f;  // valid in wave 0 lanes 0..31 (lane j owns q-row j)
  float rs_reg = 0.f;
  __syncthreads();

  f32x16 acc_o[2] = {};  // [dd]: q-row (r&3)+8*(r>>2)+4h, d-col (w*2+dd)*32+c31
  // K row base for this wave's kv rows: row = w*32 + c31 (within tile), k-off h*8
  const unsigned short* Krow = Kb + ((size_t)(w * 32 + c31)) * 512 + h * 8;
  const unsigned short* V0 = Vb + (size_t)((w * 2 + 0) * 32 + c31) * 4096;
  const unsigned short* V1 = Vb + (size_t)((w * 2 + 1) * 32 + c31) * 4096;

  for (int t = 0; t < 16; ++t) {
    const int pbuf = t & 1;
    const unsigned short* Kt = Krow + (size_t)t * 256 * 512;

    // ---- Phase A: S^T[kv 256][q 32], wave owns 32 kv rows. 32 k-steps. ----
    f32x16 accS = {};
#pragma unroll
    for (int sb = 0; sb < 8; ++sb) {
      bf16x8 kf0 = *(const bf16x8*)(Kt + (sb * 4 + 0) * 16);
      bf16x8 kf1 = *(const bf16x8*)(Kt + (sb * 4 + 1) * 16);
      bf16x8 kf2 = *(const bf16x8*)(Kt + (sb * 4 + 2) * 16);
      bf16x8 kf3 = *(const bf16x8*)(Kt + (sb * 4 + 3) * 16);
#pragma unroll
      for (int j = 0; j < 4; ++j) {
        int s = sb * 4 + j;
        int base = s * 32 + h * 16;
        int colQB = (base & ~127) | ((base & 127) ^ ((c31 & 7) << 4));
        bf16x8 qv = *(const bf16x8*)((char*)lQ + c31 * 1024 + colQB);
        bf16x8 kf = (j == 0) ? kf0 : (j == 1) ? kf1 : (j == 2) ? kf2 : kf3;
        accS = __builtin_amdgcn_mfma_f32_32x32x16_bf16(kf, qv, accS, 0, 0, 0);
      }
    }

    // ---- Phase B: online softmax (q-col = c31 per lane) ----
    float mx = accS[0];
#pragma unroll
    for (int r = 1; r < 16; ++r) mx = fmaxf(mx, accS[r]);
    mx = fmaxf(mx, __shfl_xor(mx, 32));
    if (lane < 32) redm[lane * 8 + w] = mx;
    __syncthreads();  // B1
    if (w == 0 && lane < 32) {
      f32x4 a = *(const f32x4*)&redm[lane * 8];
      f32x4 a2 = *(const f32x4*)&redm[lane * 8 + 4];
      float tmax = fmaxf(fmaxf(fmaxf(a[0], a[1]), fmaxf(a[2], a[3])),
                         fmaxf(fmaxf(a2[0], a2[1]), fmaxf(a2[2], a2[3])));
      float m_new = fmaxf(m_run, tmax);
      rs_reg = __expf(m_run - m_new);
      m_run = m_new;
      m_s[lane] = m_new;
      rs_s[lane] = rs_reg;
    }
    __syncthreads();  // B2
    // exp, row-sum, pack P -> lP[pbuf] (layout [32 q][256 kv], swizzled)
    {
      float mq = m_s[c31];
      float sum = 0.f;
#pragma unroll
      for (int j = 0; j < 4; ++j) {
        ushort4v pk;
#pragma unroll
        for (int i = 0; i < 4; ++i) {
          float p = __expf(accS[j * 4 + i] - mq);
          sum += p;
          pk[i] = f2bf(p);
        }
        // kv pos = w*32 + 8j + 4h : byte col = w*64 + j*16 + h*8
        int colB = (w * 64 + j * 16 + h * 8) ^ ((c31 & 7) << 4);
        *(ushort4v*)((char*)lP[pbuf] + c31 * 512 + colB) = pk;
      }
      sum += __shfl_xor(sum, 32);
      if (lane < 32) reds[lane * 8 + w] = sum;
    }
    // rescale acc_o while lP settles
#pragma unroll
    for (int j = 0; j < 4; ++j) {
      f32x4 rv = *(const f32x4*)&rs_s[8 * j + 4 * h];
#pragma unroll
      for (int i = 0; i < 4; ++i) {
        acc_o[0][j * 4 + i] *= rv[i];
        acc_o[1][j * 4 + i] *= rv[i];
      }
    }
    __syncthreads();  // B3
    if (w == 0 && lane < 32) {
      f32x4 a = *(const f32x4*)&reds[lane * 8];
      f32x4 a2 = *(const f32x4*)&reds[lane * 8 + 4];
      float tsum = (a[0] + a[1] + a[2] + a[3]) + (a2[0] + a2[1] + a2[2] + a2[3]);
      l_run = l_run * rs_reg + tsum;
    }

    // ---- Phase C: PV. A = P[32 q][kv] from lP, B = V frags from global. ----
    const unsigned short* Vt0 = V0 + t * 256 + h * 8;
    const unsigned short* Vt1 = V1 + t * 256 + h * 8;
#pragma unroll
    for (int kb = 0; kb < 8; ++kb) {  // 2 ks per batch
#pragma unroll
      for (int u = 0; u < 2; ++u) {
        int ks = kb * 2 + u;
        bf16x8 vf0 = *(const bf16x8*)(Vt0 + ks * 16);
        bf16x8 vf1 = *(const bf16x8*)(Vt1 + ks * 16);
        int colB = (ks * 32 + h * 16) ^ ((c31 & 7) << 4);
        bf16x8 pa = *(const bf16x8*)((char*)lP[pbuf] + c31 * 512 + colB);
        acc_o[0] = __builtin_amdgcn_mfma_f32_32x32x16_bf16(pa, vf0, acc_o[0], 0, 0, 0);
        acc_o[1] = __builtin_amdgcn_mfma_f32_32x32x16_bf16(pa, vf1, acc_o[1], 0, 0, 0);
      }
    }
    // next tile's Phase B writes lP[pbuf^1]/redm after >=1 barrier: safe.
  }

  // ---- epilogue: divide by row-sum, store fp32 ----
  if (w == 0 && lane < 32) rs_s[lane] = 1.f / l_run;
  __syncthreads();
  {
    const int q0 = qt * 32;
#pragma unroll
    for (int j = 0; j < 4; ++j) {
      f32x4 il = *(const f32x4*)&rs_s[8 * j + 4 * h];
#pragma unroll
      for (int i = 0; i < 4; ++i) {
        int qr = 8 * j + 4 * h + i;
        float* orow = out + ((size_t)b * 1024 + q0 + qr) * 512;
        orow[(w * 2 + 0) * 32 + c31] = acc_o[0][j * 4 + i] * il[i];
        orow[(w * 2 + 1) * 32 + c31] = acc_o[1][j * 4 + i] * il[i];
      }
    }
  }
}

// ---------------------------------------------------------------------------
extern "C" void kernel_launch(void* const* d_in, const int* in_sizes, int n_in,
                              void* d_out, int out_size, void* d_ws, size_t ws_size,
                              hipStream_t stream) {
  const float* query = (const float*)d_in[0];  // [16,1024,512]
  const float* keys  = (const float*)d_in[1];  // [16,4096,512]
  const float* Wq = (const float*)d_in[2];
  const float* bq = (const float*)d_in[3];
  const float* Wk = (const float*)d_in[4];
  const float* bk = (const float*)d_in[5];
  const float* Wv = (const float*)d_in[6];
  const float* bv = (const float*)d_in[7];
  float* out = (float*)d_out;

  char* w = (char*)d_ws;
  unsigned short* query_bf = (unsigned short*)w;                      // 16 MB
  unsigned short* keys_bf  = (unsigned short*)(w + 16777216);         // 64 MB
  unsigned short* q_bf = (unsigned short*)(w + 83886080);             // 16 MB
  unsigned short* k_bf = (unsigned short*)(w + 100663296);            // 64 MB
  unsigned short* vT   = (unsigned short*)(w + 167772160);            // 64 MB
  unsigned short* WqT  = (unsigned short*)(w + 234881024);
  unsigned short* WkT  = WqT + 262144;
  unsigned short* WvT  = WkT + 262144;

  const float scale = 0.04419417382415922f;  // 1/sqrt(512)

  cast_bf16_kernel<<<1024, 256, 0, stream>>>(query, query_bf, 8388608L);
  cast_bf16_kernel<<<2048, 256, 0, stream>>>(keys, keys_bf, 33554432L);
  transpose_w_kernel<<<dim3(16, 16, 3), 256, 0, stream>>>(Wq, Wk, Wv, WqT, WkT, WvT);

  // q = (query@Wq + bq) * scale   [16384 x 512]  (attention scale folded in)
  gemm_nt<0><<<dim3(4, 128), 256, 0, stream>>>(query_bf, WqT, bq, q_bf,
                                               16384, 512, 512, scale);
  // k = keys@Wk + bk    [65536 x 512]
  gemm_nt<0><<<dim3(4, 512), 256, 0, stream>>>(keys_bf, WkT, bk, k_bf,
                                               65536, 512, 512, 1.f);
  // v = k@Wv + bv, stored transposed per batch: vT[b][dim][kvpos]
  gemm_nt<1><<<dim3(4, 512), 256, 0, stream>>>(k_bf, WvT, bv, vT,
                                               65536, 512, 512, 1.f);
  // fused attention
  flash_attn<<<512, 512, 0, stream>>>(q_bf, k_bf, vT, out);

  (void)in_sizes; (void)n_in; (void)out_size; (void)ws_size;
}

// Round 6
// 629.144 us; speedup vs baseline: 1.3771x; 1.3771x over previous
//
#include <hip/hip_runtime.h>
#include <hip/hip_bf16.h>
#include <stdint.h>

// ---------------------------------------------------------------------------
// TemporalAttention fused pipeline (v6):
//   q = (query@Wq+bq)*scale ; k = keys@Wk+bk  (k_bf row-major AND kT transposed)
//   ctx0 = softmax(q k^T) @ k     (flash kernel, bf16 out)
//   out  = ctx0 @ Wv + bv         (since v = k@Wv+bv and sum(attn)=1)
// B=16, LQ=1024, LK=4096, D=512. bf16 MFMA, fp32 accum.
// ---------------------------------------------------------------------------

typedef __attribute__((ext_vector_type(8))) short bf16x8;
typedef __attribute__((ext_vector_type(4))) float f32x4;
typedef __attribute__((ext_vector_type(8))) unsigned short ushort8v;
typedef __attribute__((ext_vector_type(4))) unsigned short ushort4v;

__device__ __forceinline__ unsigned short f2bf(float f) {
  union { float f; unsigned int u; } x{f};
  unsigned int r = x.u + 0x7FFFu + ((x.u >> 16) & 1u);
  return (unsigned short)(r >> 16);
}
__device__ __forceinline__ float bf2f(unsigned short h) {
  union { unsigned int u; float f; } x{(unsigned int)h << 16};
  return x.f;
}

#define GLOAD_LDS16(gptr, lptr)                                                  \
  __builtin_amdgcn_global_load_lds((const __attribute__((address_space(1))) void*)(gptr), \
                                   (__attribute__((address_space(3))) void*)(lptr), 16, 0, 0)

// ---------------------------------------------------------------------------
// Cast fp32 -> bf16 (vectorized, grid-stride)
// ---------------------------------------------------------------------------
__global__ __launch_bounds__(256) void cast_bf16_kernel(const float* __restrict__ in,
                                                        unsigned short* __restrict__ out,
                                                        long n) {
  long i = ((long)blockIdx.x * blockDim.x + threadIdx.x) * 8;
  long stride = (long)gridDim.x * blockDim.x * 8;
  for (; i < n; i += stride) {
    const float4* p = (const float4*)(in + i);
    float4 a = p[0], b = p[1];
    ushort8v o;
    o[0] = f2bf(a.x); o[1] = f2bf(a.y); o[2] = f2bf(a.z); o[3] = f2bf(a.w);
    o[4] = f2bf(b.x); o[5] = f2bf(b.y); o[6] = f2bf(b.z); o[7] = f2bf(b.w);
    *(ushort8v*)(out + i) = o;
  }
}

// ---------------------------------------------------------------------------
// Transpose 512x512 fp32 W -> bf16 W^T (3 matrices via blockIdx.z)
// ---------------------------------------------------------------------------
__global__ __launch_bounds__(256) void transpose_w_kernel(const float* __restrict__ W0,
                                                          const float* __restrict__ W1,
                                                          const float* __restrict__ W2,
                                                          unsigned short* __restrict__ T0,
                                                          unsigned short* __restrict__ T1,
                                                          unsigned short* __restrict__ T2) {
  const float* W = (blockIdx.z == 0) ? W0 : (blockIdx.z == 1) ? W1 : W2;
  unsigned short* T = (blockIdx.z == 0) ? T0 : (blockIdx.z == 1) ? T1 : T2;
  __shared__ float tile[32][33];
  int tx = threadIdx.x & 31, ty = threadIdx.x >> 5;  // 32 x 8
  int gx = blockIdx.x * 32 + tx;
  int gy0 = blockIdx.y * 32;
#pragma unroll
  for (int i = 0; i < 32; i += 8) tile[ty + i][tx] = W[(size_t)(gy0 + ty + i) * 512 + gx];
  __syncthreads();
  int ox = blockIdx.y * 32 + tx;
  int oy0 = blockIdx.x * 32;
#pragma unroll
  for (int i = 0; i < 32; i += 8)
    T[(size_t)(oy0 + ty + i) * 512 + ox] = f2bf(tile[tx][ty + i]);
}

// ---------------------------------------------------------------------------
// NT GEMM: C[m][n] = (sum_k A[m][k]*Bt[n][k] + bias[n]) * scale
// OUT_MODE 0: bf16 C[m][n]
// OUT_MODE 2: fp32 C[m][n]
// OUT_MODE 3: dual bf16: C[m][n] row-major AND C2[(b*512+n)*4096+(m&4095)] (b=m>>12)
// Tile 128x128, BK=64, 256 threads (4 waves, 2x2), 16x16x32 bf16 MFMA.
// ---------------------------------------------------------------------------
template <int OUT_MODE>
__global__ __launch_bounds__(256, 2) void gemm_nt(const unsigned short* __restrict__ A,
                                                  const unsigned short* __restrict__ Bt,
                                                  const float* __restrict__ bias,
                                                  void* __restrict__ Cout,
                                                  void* __restrict__ Cout2,
                                                  int M, int N, int K, float scale) {
  __shared__ __align__(16) unsigned short lA[2][128][64];
  __shared__ __align__(16) unsigned short lB[2][128][64];
  const int tid = threadIdx.x;
  const int lane = tid & 63;
  const int wave = tid >> 6;
  const int m0 = blockIdx.y * 128;
  const int n0 = blockIdx.x * 128;

  f32x4 acc[4][4] = {};

  auto stage = [&](int buf, int kt) {
    const int k0 = kt * 64;
#pragma unroll
    for (int p = 0; p < 4; ++p) {
      int c = p * 4 + wave;          // chunk 0..15, 1KB each
      int f = c * 512 + lane * 8;    // flat ushort index
      int row = f >> 6, col = f & 63;
      const unsigned short* gA = A + (size_t)(m0 + row) * K + (k0 + col);
      const unsigned short* gB = Bt + (size_t)(n0 + row) * K + (k0 + col);
      GLOAD_LDS16(gA, &lA[buf][0][0] + c * 512);
      GLOAD_LDS16(gB, &lB[buf][0][0] + c * 512);
    }
  };

  const int wm = wave >> 1, wn = wave & 1;
  const int lr = lane & 15;
  const int lk = (lane >> 4) << 3;

  const int KT = K >> 6;
  stage(0, 0);
  __syncthreads();
  int cur = 0;
  for (int kt = 0; kt < KT; ++kt) {
    if (kt + 1 < KT) stage(cur ^ 1, kt + 1);
#pragma unroll
    for (int kk = 0; kk < 64; kk += 32) {
      bf16x8 af[4], bfv[4];
#pragma unroll
      for (int i = 0; i < 4; ++i)
        af[i] = *(const bf16x8*)&lA[cur][wm * 64 + i * 16 + lr][kk + lk];
#pragma unroll
      for (int j = 0; j < 4; ++j)
        bfv[j] = *(const bf16x8*)&lB[cur][wn * 64 + j * 16 + lr][kk + lk];
#pragma unroll
      for (int i = 0; i < 4; ++i)
#pragma unroll
        for (int j = 0; j < 4; ++j)
          acc[i][j] = __builtin_amdgcn_mfma_f32_16x16x32_bf16(af[i], bfv[j], acc[i][j], 0, 0, 0);
    }
    __syncthreads();
    cur ^= 1;
  }

  const int ci = lane & 15;
  const int ri = (lane >> 4) * 4;
#pragma unroll
  for (int i = 0; i < 4; ++i) {
#pragma unroll
    for (int j = 0; j < 4; ++j) {
      int gm = m0 + wm * 64 + i * 16 + ri;
      int gn = n0 + wn * 64 + j * 16 + ci;
      float bv_ = bias[gn];
      f32x4 a = acc[i][j];
      if (OUT_MODE == 0) {
        unsigned short* C = (unsigned short*)Cout;
#pragma unroll
        for (int r = 0; r < 4; ++r)
          C[(size_t)(gm + r) * N + gn] = f2bf((a[r] + bv_) * scale);
      } else if (OUT_MODE == 2) {
        float* C = (float*)Cout;
#pragma unroll
        for (int r = 0; r < 4; ++r)
          C[(size_t)(gm + r) * N + gn] = (a[r] + bv_) * scale;
      } else {  // 3: dual output (row-major + per-batch transposed)
        unsigned short* C = (unsigned short*)Cout;
        unsigned short* C2 = (unsigned short*)Cout2;
        ushort4v pk;
#pragma unroll
        for (int r = 0; r < 4; ++r) {
          unsigned short hv = f2bf((a[r] + bv_) * scale);
          C[(size_t)(gm + r) * N + gn] = hv;
          pk[r] = hv;
        }
        int b_ = gm >> 12;
        int ml = gm & 4095;
        *(ushort4v*)&C2[((size_t)b_ * 512 + gn) * 4096 + ml] = pk;
      }
    }
  }
}

// ---------------------------------------------------------------------------
// Flash attention (r4 structure): ctx0[b][q][d] = softmax_kv(q k^T) @ k
//   q: [16][1024][512] bf16 (scale pre-folded), k: [16][4096][512] bf16,
//   kT: [16][512][4096] bf16 (PV B-operand), ctx0 bf16 out.
// Block: 512 thr (8 waves), QBLK=64, KVBLK=128, 32 KV tiles, 16x16x32 MFMA.
// K and PV-operand fragments loaded DIRECT from global into VGPRs.
// Q in swizzled LDS; lP double-buffered; 3 barriers per tile.
// ---------------------------------------------------------------------------
__global__ __launch_bounds__(512, 1) void flash_attn(const unsigned short* __restrict__ q,
                                                     const unsigned short* __restrict__ k,
                                                     const unsigned short* __restrict__ kT,
                                                     unsigned short* __restrict__ ctx0) {
  __shared__ __align__(16) unsigned short lQ[64 * 512];      // 64 KB, swizzled
  __shared__ __align__(16) unsigned short lP[2][64 * 128];   // 2 x 16 KB, swizzled
  __shared__ float redm[64 * 8], reds[64 * 8];               // 4 KB
  __shared__ float m_s[64], rs_s[64];                        // 512 B

  const int tid = threadIdx.x;
  const int lane = tid & 63;
  const int w = tid >> 6;
  const int g = lane >> 4;         // quarter-wave group 0..3
  const int r16 = lane & 15;
  const int bid = blockIdx.x;
  // bijective XCD swizzle: XCD c (= bid%8) serves batches {2c, 2c+1}
  const int b = (bid & 7) * 2 + ((bid >> 3) >> 4);
  const int qt = (bid >> 3) & 15;

  const unsigned short* Qb = q + ((size_t)b * 1024 + qt * 64) * 512;
  const unsigned short* Kb = k + (size_t)b * 4096 * 512;
  const unsigned short* Vb = kT + (size_t)b * 512 * 4096;

  // prologue: stage Q via gload_lds (pre-swizzled source, linear dest)
#pragma unroll
  for (int i = 0; i < 8; ++i) {
    int byte = (i * 512 + tid) * 16;
    int row = byte >> 10;
    int colB = byte & 1023;
    int srcB = (colB & ~127) | ((colB & 127) ^ ((row & 7) << 4));
    GLOAD_LDS16(Qb + (size_t)row * 512 + (srcB >> 1), (char*)lQ + byte);
  }
  float m_run = -1e30f, l_run = 0.f;  // valid in wave 0 (lane j owns q-row j)
  float rs_reg = 0.f;
  __syncthreads();

  f32x4 acc_o[4][4] = {};  // [mf][nf]: q-row mf*16+(lane>>4)*4+r, d-col w*64+nf*16+(lane&15)
  const int rowK = w * 16 + r16;   // this wave's kv-row (within tile)
  const unsigned short* KrowBase = Kb + (size_t)rowK * 512 + (g << 3);

  for (int t = 0; t < 32; ++t) {
    const int pbuf = t & 1;
    // ---- K fragments direct from global (16 independent b128 loads) ----
    const unsigned short* Krow = KrowBase + (size_t)t * 128 * 512;
    bf16x8 kf[16];
#pragma unroll
    for (int s = 0; s < 16; ++s) kf[s] = *(const bf16x8*)(Krow + s * 32);

    // ---- Phase A: S^T = K (tile t) @ Q^T  (no barriers) ----
    f32x4 accS[4] = {};  // [nf]: kv-row rowK, q-col nf*16+(lane&15)
    __builtin_amdgcn_s_setprio(1);
#pragma unroll
    for (int s = 0; s < 16; ++s) {
#pragma unroll
      for (int nf = 0; nf < 4; ++nf) {
        int rowQ = nf * 16 + r16;
        int base = s * 64 + (g << 4);
        int colQB = (base & ~127) | ((base & 127) ^ ((rowQ & 7) << 4));
        bf16x8 qf = *(const bf16x8*)((char*)lQ + rowQ * 1024 + colQB);
        accS[nf] = __builtin_amdgcn_mfma_f32_16x16x32_bf16(kf[s], qf, accS[nf], 0, 0, 0);
      }
    }
    __builtin_amdgcn_s_setprio(0);

    // ---- PV B-operand fragments: issue early, consume in Phase C ----
    bf16x8 vf[4][4];  // [nf][ks]
#pragma unroll
    for (int nf = 0; nf < 4; ++nf) {
      int d = (w << 6) + (nf << 4) + r16;
      const unsigned short* Vrow = Vb + (size_t)d * 4096 + t * 128 + (g << 3);
#pragma unroll
      for (int ks = 0; ks < 4; ++ks) vf[nf][ks] = *(const bf16x8*)(Vrow + (ks << 5));
    }

    // ---- Phase B: online softmax ----
#pragma unroll
    for (int nf = 0; nf < 4; ++nf) {
      f32x4 s = accS[nf];
      float mx = fmaxf(fmaxf(s[0], s[1]), fmaxf(s[2], s[3]));
      mx = fmaxf(mx, __shfl_xor(mx, 16));
      mx = fmaxf(mx, __shfl_xor(mx, 32));
      if (lane < 16) redm[(nf * 16 + lane) * 8 + w] = mx;
    }
    __syncthreads();  // B1
    if (w == 0) {  // lane j owns q-row j
      f32x4 a = *(const f32x4*)&redm[lane * 8];
      f32x4 a2 = *(const f32x4*)&redm[lane * 8 + 4];
      float tmax = fmaxf(fmaxf(fmaxf(a[0], a[1]), fmaxf(a[2], a[3])),
                         fmaxf(fmaxf(a2[0], a2[1]), fmaxf(a2[2], a2[3])));
      float m_new = fmaxf(m_run, tmax);
      rs_reg = __expf(m_run - m_new);
      m_run = m_new;
      m_s[lane] = m_new;
      rs_s[lane] = rs_reg;
    }
    __syncthreads();  // B2
    // exp, row-sum, pack P -> lP[pbuf]
#pragma unroll
    for (int nf = 0; nf < 4; ++nf) {
      int qrow = nf * 16 + r16;
      float mq = m_s[qrow];
      f32x4 s = accS[nf];
      ushort4v pk;
      float sum = 0.f;
#pragma unroll
      for (int rr = 0; rr < 4; ++rr) {
        float p = __expf(s[rr] - mq);
        sum += p;
        pk[rr] = f2bf(p);
      }
      sum += __shfl_xor(sum, 16);
      sum += __shfl_xor(sum, 32);
      if (lane < 16) reds[qrow * 8 + w] = sum;
      int colB = (w * 32 + (g << 3)) ^ ((qrow & 7) << 4);
      *(ushort4v*)((char*)lP[pbuf] + qrow * 256 + colB) = pk;
    }
    // rescale output accumulator while lP settles
#pragma unroll
    for (int mf = 0; mf < 4; ++mf) {
      f32x4 rsv = *(const f32x4*)&rs_s[(mf << 4) + (g << 2)];
#pragma unroll
      for (int nf = 0; nf < 4; ++nf)
#pragma unroll
        for (int rr = 0; rr < 4; ++rr) acc_o[mf][nf][rr] *= rsv[rr];
    }
    __syncthreads();  // B3
    if (w == 0) {
      f32x4 a = *(const f32x4*)&reds[lane * 8];
      f32x4 a2 = *(const f32x4*)&reds[lane * 8 + 4];
      float tsum = (a[0] + a[1] + a[2] + a[3]) + (a2[0] + a2[1] + a2[2] + a2[3]);
      l_run = l_run * rs_reg + tsum;
    }

    // ---- Phase C: PV (A = P from lP[pbuf], B = kT frags in regs) ----
    __builtin_amdgcn_s_setprio(1);
#pragma unroll
    for (int ks = 0; ks < 4; ++ks) {
#pragma unroll
      for (int mf = 0; mf < 4; ++mf) {
        int qr = (mf << 4) + r16;
        int colB = ((ks << 6) + (g << 4)) ^ ((qr & 7) << 4);
        bf16x8 ap = *(const bf16x8*)((char*)lP[pbuf] + qr * 256 + colB);
#pragma unroll
        for (int nf = 0; nf < 4; ++nf)
          acc_o[mf][nf] = __builtin_amdgcn_mfma_f32_16x16x32_bf16(ap, vf[nf][ks], acc_o[mf][nf], 0, 0, 0);
      }
    }
    __builtin_amdgcn_s_setprio(0);
    // next tile's Phase B writes lP[pbuf^1] and redm (after B1/B2): no race with
    // this tile's lP[pbuf] reads / reds read (all separated by >=1 barrier).
  }

  // ---- epilogue: divide by row-sum, store bf16 ctx0 ----
  if (w == 0) rs_s[lane] = 1.f / l_run;
  __syncthreads();
#pragma unroll
  for (int mf = 0; mf < 4; ++mf) {
    f32x4 il = *(const f32x4*)&rs_s[(mf << 4) + (g << 2)];
#pragma unroll
    for (int nf = 0; nf < 4; ++nf) {
      int d = (w << 6) + (nf << 4) + r16;
#pragma unroll
      for (int rr = 0; rr < 4; ++rr) {
        int qr = (mf << 4) + (g << 2) + rr;
        ctx0[((size_t)b * 1024 + qt * 64 + qr) * 512 + d] = f2bf(acc_o[mf][nf][rr] * il[rr]);
      }
    }
  }
}

// ---------------------------------------------------------------------------
extern "C" void kernel_launch(void* const* d_in, const int* in_sizes, int n_in,
                              void* d_out, int out_size, void* d_ws, size_t ws_size,
                              hipStream_t stream) {
  const float* query = (const float*)d_in[0];  // [16,1024,512]
  const float* keys  = (const float*)d_in[1];  // [16,4096,512]
  const float* Wq = (const float*)d_in[2];
  const float* bq = (const float*)d_in[3];
  const float* Wk = (const float*)d_in[4];
  const float* bk = (const float*)d_in[5];
  const float* Wv = (const float*)d_in[6];
  const float* bv = (const float*)d_in[7];
  float* out = (float*)d_out;

  char* w = (char*)d_ws;
  unsigned short* query_bf = (unsigned short*)w;                      // 16 MB (dead after q-proj)
  unsigned short* keys_bf  = (unsigned short*)(w + 16777216);         // 64 MB (dead after k-proj)
  unsigned short* ctx0     = (unsigned short*)w;                      // 32 MB (overlaps dead cast bufs)
  unsigned short* q_bf = (unsigned short*)(w + 83886080);             // 16 MB
  unsigned short* k_bf = (unsigned short*)(w + 100663296);            // 64 MB
  unsigned short* kT   = (unsigned short*)(w + 167772160);            // 64 MB
  unsigned short* WqT  = (unsigned short*)(w + 234881024);
  unsigned short* WkT  = WqT + 262144;
  unsigned short* WvT  = WkT + 262144;

  const float scale = 0.04419417382415922f;  // 1/sqrt(512)

  cast_bf16_kernel<<<1024, 256, 0, stream>>>(query, query_bf, 8388608L);
  cast_bf16_kernel<<<2048, 256, 0, stream>>>(keys, keys_bf, 33554432L);
  transpose_w_kernel<<<dim3(16, 16, 3), 256, 0, stream>>>(Wq, Wk, Wv, WqT, WkT, WvT);

  // q = (query@Wq + bq) * scale   [16384 x 512]  (attention scale folded in)
  gemm_nt<0><<<dim3(4, 128), 256, 0, stream>>>(query_bf, WqT, bq, q_bf, nullptr,
                                               16384, 512, 512, scale);
  // k = keys@Wk + bk    [65536 x 512], dual output: k_bf row-major + kT per-batch transposed
  gemm_nt<3><<<dim3(4, 512), 256, 0, stream>>>(keys_bf, WkT, bk, k_bf, kT,
                                               65536, 512, 512, 1.f);
  // ctx0 = softmax(q k^T) @ k   (bf16)
  flash_attn<<<256, 512, 0, stream>>>(q_bf, k_bf, kT, ctx0);
  // out = ctx0 @ Wv + bv   (fp32)  [16384 x 512]
  gemm_nt<2><<<dim3(4, 128), 256, 0, stream>>>(ctx0, WvT, bv, out, nullptr,
                                               16384, 512, 512, 1.f);

  (void)in_sizes; (void)n_in; (void)out_size; (void)ws_size;
}